// Round 2
// baseline (83.761 us; speedup 1.0000x reference)
//
#include <hip/hip_runtime.h>

// 3D median 3x3x3, zero pad, exact. Round 9: R7 rolling-plane z-strip-of-4
// algorithm, but per-thread x-width halved 4 -> 2:
// - live set Yst[3][3][4] (36) + V[9][4] (36) + temps ~ 110 VGPR, naturally
//   under the 128 occupancy cliff -> 4 waves/SIMD WITHOUT spilling (R8's
//   forced cap spilled: live set was ~140).
// - wave spans 128 cols (float2/lane); interior halos via __shfl, the two
//   wave-edge halo values have wave-uniform addresses -> s_load + cndmask
//   into lanes 0/63 (no divergent vector loads).
// - static code ~halves (8 sel19 instances vs 16) -> less I-fetch pressure.

#define MIN3(a, b, c) fminf(fminf(a, b), c)
#define MAX3(a, b, c) fmaxf(fmaxf(a, b), c)
#define MED3(a, b, c) __builtin_amdgcn_fmed3f(a, b, c)

__device__ __forceinline__ void sort3(float &a, float &b, float &c) {
    float lo = MIN3(a, b, c);
    float hi = MAX3(a, b, c);
    float md = MED3(a, b, c);
    a = lo; b = md; c = hi;
}

// Exact median of 27 given V[line=zr*3+yr][col], z/y sorted; cols o..o+2.
__device__ __forceinline__ float sel19(const float V[9][4], int o) {
    float a0h = MAX3(V[0][o], V[0][o + 1], V[0][o + 2]);
    float a1m = MED3(V[1][o], V[1][o + 1], V[1][o + 2]);
    float a1h = MAX3(V[1][o], V[1][o + 1], V[1][o + 2]);
    float a2l = V[2][o], a2m = V[2][o + 1], a2h = V[2][o + 2];
    sort3(a2l, a2m, a2h);
    float b0m = MED3(V[3][o], V[3][o + 1], V[3][o + 2]);
    float b0h = MAX3(V[3][o], V[3][o + 1], V[3][o + 2]);
    float b1l = V[4][o], b1m = V[4][o + 1], b1h = V[4][o + 2];
    sort3(b1l, b1m, b1h);
    float b2l = MIN3(V[5][o], V[5][o + 1], V[5][o + 2]);
    float b2m = MED3(V[5][o], V[5][o + 1], V[5][o + 2]);
    float c0l = V[6][o], c0m = V[6][o + 1], c0h = V[6][o + 2];
    sort3(c0l, c0m, c0h);
    float c1l = MIN3(V[7][o], V[7][o + 1], V[7][o + 2]);
    float c1m = MED3(V[7][o], V[7][o + 1], V[7][o + 2]);
    float c2l = MIN3(V[8][o], V[8][o + 1], V[8][o + 2]);

    // Antichain exclusions (rank certificates; min/max results of the
    // unused extremes are dead-code-eliminated):
    float pa = a1m, pb = b0m, pc = b1l; sort3(pa, pb, pc);  // pa <= med
    float qa = b1h, qb = b2m, qc = c1m; sort3(qa, qb, qc);  // qc >= med
    float ra = a0h, rb = a2l, rc = c0l; sort3(ra, rb, rc);  // ra <= med
    float sa = a2h, sb = c0h, sc = c2l; sort3(sa, sb, sc);  // sc >= med
    (void)pa; (void)qc; (void)ra; (void)sc;

    float t1l = pb, t1m = pc, t1h = b1m;                    // free-sorted
    float t2l = rb, t2m = rc, t2h = a1h; sort3(t2l, t2m, t2h);
    float t3l = sa, t3m = sb, t3h = c1l; sort3(t3l, t3m, t3h);
    {
        float lam1 = MED3(t1l, t2l, t3l), lam2 = MAX3(t1l, t2l, t3l);
        float eta1 = MIN3(t1h, t2h, t3h), eta2 = MED3(t1h, t2h, t3h);
        float mu1 = t1m, mu2 = t2m, mu3 = t3m;
        t1l = lam1; t1m = lam2; t1h = qa; sort3(t1l, t1m, t1h);
        t2l = mu1;  t2m = mu2;  t2h = mu3; sort3(t2l, t2m, t2h);
        t3l = eta1; t3m = eta2; t3h = qb; sort3(t3l, t3m, t3h);
    }
    {
        float lam1 = MED3(t1l, t2l, t3l), lam2 = MAX3(t1l, t2l, t3l);
        float eta1 = MIN3(t1h, t2h, t3h), eta2 = MED3(t1h, t2h, t3h);
        float mu1 = t1m, mu2 = t2m, mu3 = t3m;
        t1l = lam1; t1m = lam2; t1h = a2m; sort3(t1l, t1m, t1h);
        t2l = mu1;  t2m = mu2;  t2h = mu3; sort3(t2l, t2m, t2h);
        t3l = eta1; t3m = eta2; t3h = c0m; sort3(t3l, t3m, t3h);
    }
    {
        float lam1 = MED3(t1l, t2l, t3l), lam2 = MAX3(t1l, t2l, t3l);
        float eta1 = MIN3(t1h, t2h, t3h), eta2 = MED3(t1h, t2h, t3h);
        float mu1 = t1m, mu2 = t2m, mu3 = t3m;
        t1l = lam1; t1m = lam2; t1h = b0h; sort3(t1l, t1m, t1h);
        t2l = mu1;  t2m = mu2;  t2h = mu3; sort3(t2l, t2m, t2h);
        t3l = eta1; t3m = eta2; t3h = b2l; sort3(t3l, t3m, t3h);
    }
    return MED3(MAX3(t1l, t2l, t3l), MED3(t1m, t2m, t3m),
                MIN3(t1h, t2h, t3h));
}

__global__ __launch_bounds__(256, 4) void median3d_kernel(
    const float *__restrict__ x, float *__restrict__ out) {
    const int W = 256, H = 256, D = 64;
    const int lane = threadIdx.x;        // wave spans 128 cols (2/lane)
    const int bx = blockIdx.x;           // 0 or 1 (x halves)
    const int xoff = bx << 7;            // 0 or 128
    const int w0 = xoff + (lane << 1);   // 2 x-outputs: w0, w0+1
    const int h = blockIdx.y * 4 + threadIdx.y;
    const int d0 = blockIdx.z * 4;       // 4 z-outputs: d0..d0+3
    const bool l0 = (lane == 0), l63 = (lane == 63);
    const bool lhalo = (bx > 0);         // wave-left halo exists in-image
    const bool rhalo = (bx == 0);        // wave-right halo exists in-image

    // Circular y-stat buffer: Yst[slot][ystat][col], slot = plane % 3.
    float Yst[3][3][4];

    // Load plane dd = d0 + p - 1 (p = 0..5) into slot, y-sorted.
    // Interior halos via __shfl; wave-edge halos (cols xoff-1, xoff+128)
    // have wave-uniform addresses -> scalar loads, cndmask'd into lanes
    // 0/63. zok&&hok is wave-uniform: scalar branch skips OOB rows.
#define LOADPLANE(P, SLOT)                                                   \
    do {                                                                     \
        const int dd = d0 + (P)-1;                                           \
        const bool zok = (unsigned)dd < (unsigned)D;                         \
        float r_[3][4];                                                      \
        _Pragma("unroll") for (int dy = 0; dy < 3; ++dy) {                   \
            const int hh = h + dy - 1;                                       \
            const bool hok = (unsigned)hh < (unsigned)H;                     \
            const int ok = __builtin_amdgcn_readfirstlane(                   \
                (int)(zok && hok));                                          \
            float2 mv = make_float2(0.0f, 0.0f);                             \
            float lt = 0.0f, rt = 0.0f;                                      \
            if (ok) {                                                        \
                const float *rowp = x + ((size_t)dd * H + hh) * W;           \
                mv = *(const float2 *)(rowp + w0);                           \
                if (lhalo) lt = rowp[xoff - 1];                              \
                if (rhalo) rt = rowp[xoff + 128];                            \
            }                                                                \
            float lsh = __shfl_up(mv.y, 1);                                  \
            float rsh = __shfl_down(mv.x, 1);                                \
            r_[dy][0] = l0 ? lt : lsh;                                       \
            r_[dy][1] = mv.x;                                                \
            r_[dy][2] = mv.y;                                                \
            r_[dy][3] = l63 ? rt : rsh;                                      \
        }                                                                    \
        _Pragma("unroll") for (int c = 0; c < 4; ++c) {                      \
            sort3(r_[0][c], r_[1][c], r_[2][c]);                             \
            Yst[SLOT][0][c] = r_[0][c];                                      \
            Yst[SLOT][1][c] = r_[1][c];                                      \
            Yst[SLOT][2][c] = r_[2][c];                                      \
        }                                                                    \
    } while (0)

    LOADPLANE(0, 0);
    LOADPLANE(1, 1);

#pragma unroll
    for (int zo = 0; zo < 4; ++zo) {
        // Bring in plane zo+2 (slot (zo+2)%3), overwriting the expired one.
        switch ((zo + 2) % 3) {
            case 0: LOADPLANE(zo + 2, 0); break;
            case 1: LOADPLANE(zo + 2, 1); break;
            default: LOADPLANE(zo + 2, 2); break;
        }
        const int sA = zo % 3, sB = (zo + 1) % 3, sC = (zo + 2) % 3;
        // z-sort the 3 y-stats across the window planes -> V lines.
        float V[9][4];
#pragma unroll
        for (int yr = 0; yr < 3; ++yr)
#pragma unroll
            for (int c = 0; c < 4; ++c) {
                float a = Yst[sA][yr][c];
                float b = Yst[sB][yr][c];
                float cc = Yst[sC][yr][c];
                sort3(a, b, cc);
                V[0 + yr][c] = a;
                V[3 + yr][c] = b;
                V[6 + yr][c] = cc;
            }
        float2 r2;
        r2.x = sel19(V, 0);
        r2.y = sel19(V, 1);
        *(float2 *)(out + (size_t)((d0 + zo) * H + h) * W + w0) = r2;
    }
#undef LOADPLANE
}

extern "C" void kernel_launch(void *const *d_in, const int *in_sizes, int n_in,
                              void *d_out, int out_size, void *d_ws,
                              size_t ws_size, hipStream_t stream) {
    const float *x = (const float *)d_in[0];
    float *out = (float *)d_out;
    dim3 block(64, 4, 1);
    dim3 grid(2, 256 / 4, 64 / 4);
    median3d_kernel<<<grid, block, 0, stream>>>(x, out);
}

// Round 3
// 81.365 us; speedup vs baseline: 1.0294x; 1.0294x over previous
//
#include <hip/hip_runtime.h>

// 3D median 3x3x3, zero pad, exact. Round 10: R9 width-2 rolling-plane
// algorithm, restructured for PREFETCH DISTANCE:
// - plane loads split into ISSUE (global loads -> regs, fire-and-forget)
//   and COMMIT (shfl + y-sort -> rolling slot). Plane zo+3 is ISSUEd before
//   the z-sort/sel19 compute of iteration zo, so its ~200-600 cyc L2/L3
//   latency hides under ~600 cyc of independent ALU work (R7-R9 consumed
//   each plane's loads immediately -> latency on the critical path).
// - natural register allocation (__launch_bounds__(256) only): R8/R9's
//   forced min-waves=4 capped VGPR<=128 and spilled/over-constrained.

#define MIN3(a, b, c) fminf(fminf(a, b), c)
#define MAX3(a, b, c) fmaxf(fmaxf(a, b), c)
#define MED3(a, b, c) __builtin_amdgcn_fmed3f(a, b, c)

__device__ __forceinline__ void sort3(float &a, float &b, float &c) {
    float lo = MIN3(a, b, c);
    float hi = MAX3(a, b, c);
    float md = MED3(a, b, c);
    a = lo; b = md; c = hi;
}

// Exact median of 27 given V[line=zr*3+yr][col], z/y sorted; cols o..o+2.
__device__ __forceinline__ float sel19(const float V[9][4], int o) {
    float a0h = MAX3(V[0][o], V[0][o + 1], V[0][o + 2]);
    float a1m = MED3(V[1][o], V[1][o + 1], V[1][o + 2]);
    float a1h = MAX3(V[1][o], V[1][o + 1], V[1][o + 2]);
    float a2l = V[2][o], a2m = V[2][o + 1], a2h = V[2][o + 2];
    sort3(a2l, a2m, a2h);
    float b0m = MED3(V[3][o], V[3][o + 1], V[3][o + 2]);
    float b0h = MAX3(V[3][o], V[3][o + 1], V[3][o + 2]);
    float b1l = V[4][o], b1m = V[4][o + 1], b1h = V[4][o + 2];
    sort3(b1l, b1m, b1h);
    float b2l = MIN3(V[5][o], V[5][o + 1], V[5][o + 2]);
    float b2m = MED3(V[5][o], V[5][o + 1], V[5][o + 2]);
    float c0l = V[6][o], c0m = V[6][o + 1], c0h = V[6][o + 2];
    sort3(c0l, c0m, c0h);
    float c1l = MIN3(V[7][o], V[7][o + 1], V[7][o + 2]);
    float c1m = MED3(V[7][o], V[7][o + 1], V[7][o + 2]);
    float c2l = MIN3(V[8][o], V[8][o + 1], V[8][o + 2]);

    // Antichain exclusions (rank certificates; min/max results of the
    // unused extremes are dead-code-eliminated):
    float pa = a1m, pb = b0m, pc = b1l; sort3(pa, pb, pc);  // pa <= med
    float qa = b1h, qb = b2m, qc = c1m; sort3(qa, qb, qc);  // qc >= med
    float ra = a0h, rb = a2l, rc = c0l; sort3(ra, rb, rc);  // ra <= med
    float sa = a2h, sb = c0h, sc = c2l; sort3(sa, sb, sc);  // sc >= med
    (void)pa; (void)qc; (void)ra; (void)sc;

    float t1l = pb, t1m = pc, t1h = b1m;                    // free-sorted
    float t2l = rb, t2m = rc, t2h = a1h; sort3(t2l, t2m, t2h);
    float t3l = sa, t3m = sb, t3h = c1l; sort3(t3l, t3m, t3h);
    {
        float lam1 = MED3(t1l, t2l, t3l), lam2 = MAX3(t1l, t2l, t3l);
        float eta1 = MIN3(t1h, t2h, t3h), eta2 = MED3(t1h, t2h, t3h);
        float mu1 = t1m, mu2 = t2m, mu3 = t3m;
        t1l = lam1; t1m = lam2; t1h = qa; sort3(t1l, t1m, t1h);
        t2l = mu1;  t2m = mu2;  t2h = mu3; sort3(t2l, t2m, t2h);
        t3l = eta1; t3m = eta2; t3h = qb; sort3(t3l, t3m, t3h);
    }
    {
        float lam1 = MED3(t1l, t2l, t3l), lam2 = MAX3(t1l, t2l, t3l);
        float eta1 = MIN3(t1h, t2h, t3h), eta2 = MED3(t1h, t2h, t3h);
        float mu1 = t1m, mu2 = t2m, mu3 = t3m;
        t1l = lam1; t1m = lam2; t1h = a2m; sort3(t1l, t1m, t1h);
        t2l = mu1;  t2m = mu2;  t2h = mu3; sort3(t2l, t2m, t2h);
        t3l = eta1; t3m = eta2; t3h = c0m; sort3(t3l, t3m, t3h);
    }
    {
        float lam1 = MED3(t1l, t2l, t3l), lam2 = MAX3(t1l, t2l, t3l);
        float eta1 = MIN3(t1h, t2h, t3h), eta2 = MED3(t1h, t2h, t3h);
        float mu1 = t1m, mu2 = t2m, mu3 = t3m;
        t1l = lam1; t1m = lam2; t1h = b0h; sort3(t1l, t1m, t1h);
        t2l = mu1;  t2m = mu2;  t2h = mu3; sort3(t2l, t2m, t2h);
        t3l = eta1; t3m = eta2; t3h = b2l; sort3(t3l, t3m, t3h);
    }
    return MED3(MAX3(t1l, t2l, t3l), MED3(t1m, t2m, t3m),
                MIN3(t1h, t2h, t3h));
}

__global__ __launch_bounds__(256) void median3d_kernel(
    const float *__restrict__ x, float *__restrict__ out) {
    const int W = 256, H = 256, D = 64;
    const int lane = threadIdx.x;        // wave spans 128 cols (2/lane)
    const int bx = blockIdx.x;           // 0 or 1 (x halves)
    const int xoff = bx << 7;            // 0 or 128
    const int w0 = xoff + (lane << 1);   // 2 x-outputs: w0, w0+1
    const int h = blockIdx.y * 4 + threadIdx.y;
    const int d0 = blockIdx.z * 4;       // 4 z-outputs: d0..d0+3
    const bool l0 = (lane == 0), l63 = (lane == 63);
    const bool lhalo = (bx > 0);         // wave-left halo exists in-image
    const bool rhalo = (bx == 0);        // wave-right halo exists in-image

    // Circular y-stat buffer: Yst[slot][ystat][col], slot = plane % 3.
    float Yst[3][3][4];

    // In-flight plane registers (SSA-renamed per unrolled instance).
    float2 mv_[3];
    float lt_[3], rt_[3];

    // ISSUE: fire the 3 row loads (+ wave-edge halos) for plane
    // dd = d0 + P - 1 into registers. No consumer here -> stays in flight.
#define ISSUE(P)                                                             \
    do {                                                                     \
        const int dd = d0 + (P)-1;                                           \
        const bool zok = (unsigned)dd < (unsigned)D;                         \
        _Pragma("unroll") for (int dy = 0; dy < 3; ++dy) {                   \
            const int hh = h + dy - 1;                                       \
            const bool hok = (unsigned)hh < (unsigned)H;                     \
            const int ok = __builtin_amdgcn_readfirstlane(                   \
                (int)(zok && hok));                                          \
            mv_[dy] = make_float2(0.0f, 0.0f);                               \
            lt_[dy] = 0.0f;                                                  \
            rt_[dy] = 0.0f;                                                  \
            if (ok) {                                                        \
                const float *rowp = x + ((size_t)dd * H + hh) * W;           \
                mv_[dy] = *(const float2 *)(rowp + w0);                      \
                if (lhalo) lt_[dy] = rowp[xoff - 1];                         \
                if (rhalo) rt_[dy] = rowp[xoff + 128];                       \
            }                                                                \
        }                                                                    \
    } while (0)

    // COMMIT: halo shuffles + y-sort of the in-flight plane into slot SLOT.
#define COMMIT(SLOT)                                                         \
    do {                                                                     \
        float r_[3][4];                                                      \
        _Pragma("unroll") for (int dy = 0; dy < 3; ++dy) {                   \
            float lsh = __shfl_up(mv_[dy].y, 1);                             \
            float rsh = __shfl_down(mv_[dy].x, 1);                           \
            r_[dy][0] = l0 ? lt_[dy] : lsh;                                  \
            r_[dy][1] = mv_[dy].x;                                           \
            r_[dy][2] = mv_[dy].y;                                           \
            r_[dy][3] = l63 ? rt_[dy] : rsh;                                 \
        }                                                                    \
        _Pragma("unroll") for (int c = 0; c < 4; ++c) {                      \
            sort3(r_[0][c], r_[1][c], r_[2][c]);                             \
            Yst[SLOT][0][c] = r_[0][c];                                      \
            Yst[SLOT][1][c] = r_[1][c];                                      \
            Yst[SLOT][2][c] = r_[2][c];                                      \
        }                                                                    \
    } while (0)

    ISSUE(0); COMMIT(0);
    ISSUE(1); COMMIT(1);
    ISSUE(2);  // plane 2 rides over nothing yet; committed at zo=0 below

#pragma unroll
    for (int zo = 0; zo < 4; ++zo) {
        // Land the in-flight plane zo+2 into its slot.
        switch ((zo + 2) % 3) {
            case 0: COMMIT(0); break;
            case 1: COMMIT(1); break;
            default: COMMIT(2); break;
        }
        // Prefetch plane zo+3: its latency hides under the sel19s below.
        if (zo < 3) {
            switch (zo) {
                case 0: ISSUE(3); break;
                case 1: ISSUE(4); break;
                default: ISSUE(5); break;
            }
        }
        const int sA = zo % 3, sB = (zo + 1) % 3, sC = (zo + 2) % 3;
        // z-sort the 3 y-stats across the window planes -> V lines.
        float V[9][4];
#pragma unroll
        for (int yr = 0; yr < 3; ++yr)
#pragma unroll
            for (int c = 0; c < 4; ++c) {
                float a = Yst[sA][yr][c];
                float b = Yst[sB][yr][c];
                float cc = Yst[sC][yr][c];
                sort3(a, b, cc);
                V[0 + yr][c] = a;
                V[3 + yr][c] = b;
                V[6 + yr][c] = cc;
            }
        float2 r2;
        r2.x = sel19(V, 0);
        r2.y = sel19(V, 1);
        *(float2 *)(out + (size_t)((d0 + zo) * H + h) * W + w0) = r2;
    }
#undef ISSUE
#undef COMMIT
}

extern "C" void kernel_launch(void *const *d_in, const int *in_sizes, int n_in,
                              void *d_out, int out_size, void *d_ws,
                              size_t ws_size, hipStream_t stream) {
    const float *x = (const float *)d_in[0];
    float *out = (float *)d_out;
    dim3 block(64, 4, 1);
    dim3 grid(2, 256 / 4, 64 / 4);
    median3d_kernel<<<grid, block, 0, stream>>>(x, out);
}

// Round 4
// 80.524 us; speedup vs baseline: 1.0402x; 1.0104x over previous
//
#include <hip/hip_runtime.h>

// 3D median 3x3x3, zero pad, exact. Round 11: best-of-breed combination.
// Base = R7 width-4 z-strip-4 rolling-plane (the 79.8 us champion), plus the
// two levers that each showed positive/neutral marginals on inferior bases:
// - shuffle halos + wave-uniform row masking (R8): halo cols w0-1/w0+4 come
//   from neighbor lanes' float4 via __shfl (wave spans the full 256 row);
//   OOB rows skipped by a scalar branch (zok&&hok wave-uniform) -> no
//   per-lane cndmask walls, 6 fewer loads/plane.
// - ISSUE/COMMIT prefetch split (R10) with TWO in-flight register sets
//   (A/B double-buffer): plane p's loads are issued one full iteration
//   (~700 cyc of sel19 work) before their COMMIT consumes them, and the
//   A/B alternation removes the WAR hazard on re-issue.
// - natural allocation (__launch_bounds__(256)): ~170 VGPR, 2 waves/SIMD,
//   no spill (R8/R9's forced min-waves=4 was counterproductive).

#define MIN3(a, b, c) fminf(fminf(a, b), c)
#define MAX3(a, b, c) fmaxf(fmaxf(a, b), c)
#define MED3(a, b, c) __builtin_amdgcn_fmed3f(a, b, c)

__device__ __forceinline__ void sort3(float &a, float &b, float &c) {
    float lo = MIN3(a, b, c);
    float hi = MAX3(a, b, c);
    float md = MED3(a, b, c);
    a = lo; b = md; c = hi;
}

// Exact median of 27 given V[line=zr*3+yr][col], z/y sorted; cols o..o+2.
__device__ __forceinline__ float sel19(const float V[9][6], int o) {
    float a0h = MAX3(V[0][o], V[0][o + 1], V[0][o + 2]);
    float a1m = MED3(V[1][o], V[1][o + 1], V[1][o + 2]);
    float a1h = MAX3(V[1][o], V[1][o + 1], V[1][o + 2]);
    float a2l = V[2][o], a2m = V[2][o + 1], a2h = V[2][o + 2];
    sort3(a2l, a2m, a2h);
    float b0m = MED3(V[3][o], V[3][o + 1], V[3][o + 2]);
    float b0h = MAX3(V[3][o], V[3][o + 1], V[3][o + 2]);
    float b1l = V[4][o], b1m = V[4][o + 1], b1h = V[4][o + 2];
    sort3(b1l, b1m, b1h);
    float b2l = MIN3(V[5][o], V[5][o + 1], V[5][o + 2]);
    float b2m = MED3(V[5][o], V[5][o + 1], V[5][o + 2]);
    float c0l = V[6][o], c0m = V[6][o + 1], c0h = V[6][o + 2];
    sort3(c0l, c0m, c0h);
    float c1l = MIN3(V[7][o], V[7][o + 1], V[7][o + 2]);
    float c1m = MED3(V[7][o], V[7][o + 1], V[7][o + 2]);
    float c2l = MIN3(V[8][o], V[8][o + 1], V[8][o + 2]);

    // Antichain exclusions (rank certificates; min/max results of the
    // unused extremes are dead-code-eliminated):
    float pa = a1m, pb = b0m, pc = b1l; sort3(pa, pb, pc);  // pa <= med
    float qa = b1h, qb = b2m, qc = c1m; sort3(qa, qb, qc);  // qc >= med
    float ra = a0h, rb = a2l, rc = c0l; sort3(ra, rb, rc);  // ra <= med
    float sa = a2h, sb = c0h, sc = c2l; sort3(sa, sb, sc);  // sc >= med
    (void)pa; (void)qc; (void)ra; (void)sc;

    float t1l = pb, t1m = pc, t1h = b1m;                    // free-sorted
    float t2l = rb, t2m = rc, t2h = a1h; sort3(t2l, t2m, t2h);
    float t3l = sa, t3m = sb, t3h = c1l; sort3(t3l, t3m, t3h);
    {
        float lam1 = MED3(t1l, t2l, t3l), lam2 = MAX3(t1l, t2l, t3l);
        float eta1 = MIN3(t1h, t2h, t3h), eta2 = MED3(t1h, t2h, t3h);
        float mu1 = t1m, mu2 = t2m, mu3 = t3m;
        t1l = lam1; t1m = lam2; t1h = qa; sort3(t1l, t1m, t1h);
        t2l = mu1;  t2m = mu2;  t2h = mu3; sort3(t2l, t2m, t2h);
        t3l = eta1; t3m = eta2; t3h = qb; sort3(t3l, t3m, t3h);
    }
    {
        float lam1 = MED3(t1l, t2l, t3l), lam2 = MAX3(t1l, t2l, t3l);
        float eta1 = MIN3(t1h, t2h, t3h), eta2 = MED3(t1h, t2h, t3h);
        float mu1 = t1m, mu2 = t2m, mu3 = t3m;
        t1l = lam1; t1m = lam2; t1h = a2m; sort3(t1l, t1m, t1h);
        t2l = mu1;  t2m = mu2;  t2h = mu3; sort3(t2l, t2m, t2h);
        t3l = eta1; t3m = eta2; t3h = c0m; sort3(t3l, t3m, t3h);
    }
    {
        float lam1 = MED3(t1l, t2l, t3l), lam2 = MAX3(t1l, t2l, t3l);
        float eta1 = MIN3(t1h, t2h, t3h), eta2 = MED3(t1h, t2h, t3h);
        float mu1 = t1m, mu2 = t2m, mu3 = t3m;
        t1l = lam1; t1m = lam2; t1h = b0h; sort3(t1l, t1m, t1h);
        t2l = mu1;  t2m = mu2;  t2h = mu3; sort3(t2l, t2m, t2h);
        t3l = eta1; t3m = eta2; t3h = b2l; sort3(t3l, t3m, t3h);
    }
    return MED3(MAX3(t1l, t2l, t3l), MED3(t1m, t2m, t3m),
                MIN3(t1h, t2h, t3h));
}

__global__ __launch_bounds__(256) void median3d_kernel(
    const float *__restrict__ x, float *__restrict__ out) {
    const int W = 256, H = 256, D = 64;
    const int lane = threadIdx.x;   // wave spans full 256-wide x row
    const int w0 = lane << 2;       // 4 x-outputs
    const int h = blockIdx.y * 4 + threadIdx.y;
    const int d0 = blockIdx.z * 4;  // 4 z-outputs: d0..d0+3
    const bool lval = (lane != 0), rval = (lane != 63);

    // Circular y-stat buffer: Yst[slot][ystat][col], slot = plane % 3.
    float Yst[3][3][6];

    // Two in-flight plane register sets (A/B double-buffer).
    float4 mvA[3], mvB[3];

    // ISSUE: fire plane dd = d0 + P - 1's 3 row loads into register set SET.
    // zok && hok is wave-uniform (blockDim.x == 64): scalar branch, OOB rows
    // skip the load entirely (value 0 = zero pad).
#define ISSUE(P, SET)                                                        \
    do {                                                                     \
        const int dd = d0 + (P)-1;                                           \
        const bool zok = (unsigned)dd < (unsigned)D;                         \
        _Pragma("unroll") for (int dy = 0; dy < 3; ++dy) {                   \
            const int hh = h + dy - 1;                                       \
            const bool hok = (unsigned)hh < (unsigned)H;                     \
            const int ok = __builtin_amdgcn_readfirstlane(                   \
                (int)(zok && hok));                                          \
            SET[dy] = make_float4(0.0f, 0.0f, 0.0f, 0.0f);                   \
            if (ok)                                                          \
                SET[dy] =                                                    \
                    *(const float4 *)(x + ((size_t)dd * H + hh) * W + w0);   \
        }                                                                    \
    } while (0)

    // COMMIT: halo shuffles + y-sort of in-flight set SET into slot SLOT.
    // Halo cols (w0-1, w0+4) come from neighbor lanes' float4 via __shfl;
    // lane 0/63 edges are the image border -> zero pad via lval/rval.
#define COMMIT(SET, SLOT)                                                    \
    do {                                                                     \
        float r_[3][6];                                                      \
        _Pragma("unroll") for (int dy = 0; dy < 3; ++dy) {                   \
            const float lsh = __shfl_up(SET[dy].w, 1);                       \
            const float rsh = __shfl_down(SET[dy].x, 1);                     \
            r_[dy][0] = lval ? lsh : 0.0f;                                   \
            r_[dy][1] = SET[dy].x;                                           \
            r_[dy][2] = SET[dy].y;                                           \
            r_[dy][3] = SET[dy].z;                                           \
            r_[dy][4] = SET[dy].w;                                           \
            r_[dy][5] = rval ? rsh : 0.0f;                                   \
        }                                                                    \
        _Pragma("unroll") for (int c = 0; c < 6; ++c) {                      \
            sort3(r_[0][c], r_[1][c], r_[2][c]);                             \
            Yst[SLOT][0][c] = r_[0][c];                                      \
            Yst[SLOT][1][c] = r_[1][c];                                      \
            Yst[SLOT][2][c] = r_[2][c];                                      \
        }                                                                    \
    } while (0)

    // COMPUTE(ZO, SA, SB, SC): z-sort slots -> V, 4x sel19, store row.
#define COMPUTE(ZO, SA, SB, SC)                                              \
    do {                                                                     \
        float V[9][6];                                                       \
        _Pragma("unroll") for (int yr = 0; yr < 3; ++yr)                     \
            _Pragma("unroll") for (int c = 0; c < 6; ++c) {                  \
                float a = Yst[SA][yr][c];                                    \
                float b = Yst[SB][yr][c];                                    \
                float cc = Yst[SC][yr][c];                                   \
                sort3(a, b, cc);                                             \
                V[0 + yr][c] = a;                                            \
                V[3 + yr][c] = b;                                            \
                V[6 + yr][c] = cc;                                           \
            }                                                                \
        float4 r4;                                                           \
        r4.x = sel19(V, 0);                                                  \
        r4.y = sel19(V, 1);                                                  \
        r4.z = sel19(V, 2);                                                  \
        r4.w = sel19(V, 3);                                                  \
        *(float4 *)(out + (size_t)((d0 + (ZO)) * H + h) * W + w0) = r4;      \
    } while (0)

    // Pipeline: plane p lives in set (p & 1); slot for plane p = p % 3.
    ISSUE(0, mvA);
    ISSUE(1, mvB);
    COMMIT(mvA, 0);
    ISSUE(2, mvA);
    COMMIT(mvB, 1);
    ISSUE(3, mvB);

    // zo = 0: commit plane 2, prefetch plane 4, compute.
    COMMIT(mvA, 2);
    ISSUE(4, mvA);
    COMPUTE(0, 0, 1, 2);

    // zo = 1: commit plane 3, prefetch plane 5, compute.
    COMMIT(mvB, 0);
    ISSUE(5, mvB);
    COMPUTE(1, 1, 2, 0);

    // zo = 2: commit plane 4, compute.
    COMMIT(mvA, 1);
    COMPUTE(2, 2, 0, 1);

    // zo = 3: commit plane 5, compute.
    COMMIT(mvB, 2);
    COMPUTE(3, 0, 1, 2);

#undef ISSUE
#undef COMMIT
#undef COMPUTE
}

extern "C" void kernel_launch(void *const *d_in, const int *in_sizes, int n_in,
                              void *d_out, int out_size, void *d_ws,
                              size_t ws_size, hipStream_t stream) {
    const float *x = (const float *)d_in[0];
    float *out = (float *)d_out;
    dim3 block(64, 4, 1);
    dim3 grid(1, 256 / 4, 64 / 4);
    median3d_kernel<<<grid, block, 0, stream>>>(x, out);
}

// Round 5
// 80.128 us; speedup vs baseline: 1.0453x; 1.0049x over previous
//
#include <hip/hip_runtime.h>

// 3D median 3x3x3, zero pad, exact. Round 12: R11 pipeline (width-4
// z-strip-4 rolling planes, shuffle halos, wave-uniform row masking, A/B
// double-buffered ISSUE/COMMIT prefetch) with ONE change:
// __launch_bounds__(256, 3).
// Occupancy model (m69): waves/SIMD = floor(512 / VGPR rounded to granule 8).
// R11 allocated ~170-180 VGPR -> 2 waves/SIMD; the 3-wave bucket starts at
// VGPR <= 168 and was never targeted (R8/R9 jumped to the 4-wave/128 bucket,
// needing -40 regs -> spill). Capping at 168 costs ~10 regs of scheduling
// freedom but adds a third wave to cover simultaneous-waitcnt stalls that
// reordering could not touch (R10/R11 prefetch nulls).

#define MIN3(a, b, c) fminf(fminf(a, b), c)
#define MAX3(a, b, c) fmaxf(fmaxf(a, b), c)
#define MED3(a, b, c) __builtin_amdgcn_fmed3f(a, b, c)

__device__ __forceinline__ void sort3(float &a, float &b, float &c) {
    float lo = MIN3(a, b, c);
    float hi = MAX3(a, b, c);
    float md = MED3(a, b, c);
    a = lo; b = md; c = hi;
}

// Exact median of 27 given V[line=zr*3+yr][col], z/y sorted; cols o..o+2.
__device__ __forceinline__ float sel19(const float V[9][6], int o) {
    float a0h = MAX3(V[0][o], V[0][o + 1], V[0][o + 2]);
    float a1m = MED3(V[1][o], V[1][o + 1], V[1][o + 2]);
    float a1h = MAX3(V[1][o], V[1][o + 1], V[1][o + 2]);
    float a2l = V[2][o], a2m = V[2][o + 1], a2h = V[2][o + 2];
    sort3(a2l, a2m, a2h);
    float b0m = MED3(V[3][o], V[3][o + 1], V[3][o + 2]);
    float b0h = MAX3(V[3][o], V[3][o + 1], V[3][o + 2]);
    float b1l = V[4][o], b1m = V[4][o + 1], b1h = V[4][o + 2];
    sort3(b1l, b1m, b1h);
    float b2l = MIN3(V[5][o], V[5][o + 1], V[5][o + 2]);
    float b2m = MED3(V[5][o], V[5][o + 1], V[5][o + 2]);
    float c0l = V[6][o], c0m = V[6][o + 1], c0h = V[6][o + 2];
    sort3(c0l, c0m, c0h);
    float c1l = MIN3(V[7][o], V[7][o + 1], V[7][o + 2]);
    float c1m = MED3(V[7][o], V[7][o + 1], V[7][o + 2]);
    float c2l = MIN3(V[8][o], V[8][o + 1], V[8][o + 2]);

    // Antichain exclusions (rank certificates; min/max results of the
    // unused extremes are dead-code-eliminated):
    float pa = a1m, pb = b0m, pc = b1l; sort3(pa, pb, pc);  // pa <= med
    float qa = b1h, qb = b2m, qc = c1m; sort3(qa, qb, qc);  // qc >= med
    float ra = a0h, rb = a2l, rc = c0l; sort3(ra, rb, rc);  // ra <= med
    float sa = a2h, sb = c0h, sc = c2l; sort3(sa, sb, sc);  // sc >= med
    (void)pa; (void)qc; (void)ra; (void)sc;

    float t1l = pb, t1m = pc, t1h = b1m;                    // free-sorted
    float t2l = rb, t2m = rc, t2h = a1h; sort3(t2l, t2m, t2h);
    float t3l = sa, t3m = sb, t3h = c1l; sort3(t3l, t3m, t3h);
    {
        float lam1 = MED3(t1l, t2l, t3l), lam2 = MAX3(t1l, t2l, t3l);
        float eta1 = MIN3(t1h, t2h, t3h), eta2 = MED3(t1h, t2h, t3h);
        float mu1 = t1m, mu2 = t2m, mu3 = t3m;
        t1l = lam1; t1m = lam2; t1h = qa; sort3(t1l, t1m, t1h);
        t2l = mu1;  t2m = mu2;  t2h = mu3; sort3(t2l, t2m, t2h);
        t3l = eta1; t3m = eta2; t3h = qb; sort3(t3l, t3m, t3h);
    }
    {
        float lam1 = MED3(t1l, t2l, t3l), lam2 = MAX3(t1l, t2l, t3l);
        float eta1 = MIN3(t1h, t2h, t3h), eta2 = MED3(t1h, t2h, t3h);
        float mu1 = t1m, mu2 = t2m, mu3 = t3m;
        t1l = lam1; t1m = lam2; t1h = a2m; sort3(t1l, t1m, t1h);
        t2l = mu1;  t2m = mu2;  t2h = mu3; sort3(t2l, t2m, t2h);
        t3l = eta1; t3m = eta2; t3h = c0m; sort3(t3l, t3m, t3h);
    }
    {
        float lam1 = MED3(t1l, t2l, t3l), lam2 = MAX3(t1l, t2l, t3l);
        float eta1 = MIN3(t1h, t2h, t3h), eta2 = MED3(t1h, t2h, t3h);
        float mu1 = t1m, mu2 = t2m, mu3 = t3m;
        t1l = lam1; t1m = lam2; t1h = b0h; sort3(t1l, t1m, t1h);
        t2l = mu1;  t2m = mu2;  t2h = mu3; sort3(t2l, t2m, t2h);
        t3l = eta1; t3m = eta2; t3h = b2l; sort3(t3l, t3m, t3h);
    }
    return MED3(MAX3(t1l, t2l, t3l), MED3(t1m, t2m, t3m),
                MIN3(t1h, t2h, t3h));
}

__global__ __launch_bounds__(256, 3) void median3d_kernel(
    const float *__restrict__ x, float *__restrict__ out) {
    const int W = 256, H = 256, D = 64;
    const int lane = threadIdx.x;   // wave spans full 256-wide x row
    const int w0 = lane << 2;       // 4 x-outputs
    const int h = blockIdx.y * 4 + threadIdx.y;
    const int d0 = blockIdx.z * 4;  // 4 z-outputs: d0..d0+3
    const bool lval = (lane != 0), rval = (lane != 63);

    // Circular y-stat buffer: Yst[slot][ystat][col], slot = plane % 3.
    float Yst[3][3][6];

    // Two in-flight plane register sets (A/B double-buffer).
    float4 mvA[3], mvB[3];

    // ISSUE: fire plane dd = d0 + P - 1's 3 row loads into register set SET.
    // zok && hok is wave-uniform (blockDim.x == 64): scalar branch, OOB rows
    // skip the load entirely (value 0 = zero pad).
#define ISSUE(P, SET)                                                        \
    do {                                                                     \
        const int dd = d0 + (P)-1;                                           \
        const bool zok = (unsigned)dd < (unsigned)D;                         \
        _Pragma("unroll") for (int dy = 0; dy < 3; ++dy) {                   \
            const int hh = h + dy - 1;                                       \
            const bool hok = (unsigned)hh < (unsigned)H;                     \
            const int ok = __builtin_amdgcn_readfirstlane(                   \
                (int)(zok && hok));                                          \
            SET[dy] = make_float4(0.0f, 0.0f, 0.0f, 0.0f);                   \
            if (ok)                                                          \
                SET[dy] =                                                    \
                    *(const float4 *)(x + ((size_t)dd * H + hh) * W + w0);   \
        }                                                                    \
    } while (0)

    // COMMIT: halo shuffles + y-sort of in-flight set SET into slot SLOT.
    // Halo cols (w0-1, w0+4) come from neighbor lanes' float4 via __shfl;
    // lane 0/63 edges are the image border -> zero pad via lval/rval.
#define COMMIT(SET, SLOT)                                                    \
    do {                                                                     \
        float r_[3][6];                                                      \
        _Pragma("unroll") for (int dy = 0; dy < 3; ++dy) {                   \
            const float lsh = __shfl_up(SET[dy].w, 1);                       \
            const float rsh = __shfl_down(SET[dy].x, 1);                     \
            r_[dy][0] = lval ? lsh : 0.0f;                                   \
            r_[dy][1] = SET[dy].x;                                           \
            r_[dy][2] = SET[dy].y;                                           \
            r_[dy][3] = SET[dy].z;                                           \
            r_[dy][4] = SET[dy].w;                                           \
            r_[dy][5] = rval ? rsh : 0.0f;                                   \
        }                                                                    \
        _Pragma("unroll") for (int c = 0; c < 6; ++c) {                      \
            sort3(r_[0][c], r_[1][c], r_[2][c]);                             \
            Yst[SLOT][0][c] = r_[0][c];                                      \
            Yst[SLOT][1][c] = r_[1][c];                                      \
            Yst[SLOT][2][c] = r_[2][c];                                      \
        }                                                                    \
    } while (0)

    // COMPUTE(ZO, SA, SB, SC): z-sort slots -> V, 4x sel19, store row.
#define COMPUTE(ZO, SA, SB, SC)                                              \
    do {                                                                     \
        float V[9][6];                                                       \
        _Pragma("unroll") for (int yr = 0; yr < 3; ++yr)                     \
            _Pragma("unroll") for (int c = 0; c < 6; ++c) {                  \
                float a = Yst[SA][yr][c];                                    \
                float b = Yst[SB][yr][c];                                    \
                float cc = Yst[SC][yr][c];                                   \
                sort3(a, b, cc);                                             \
                V[0 + yr][c] = a;                                            \
                V[3 + yr][c] = b;                                            \
                V[6 + yr][c] = cc;                                           \
            }                                                                \
        float4 r4;                                                           \
        r4.x = sel19(V, 0);                                                  \
        r4.y = sel19(V, 1);                                                  \
        r4.z = sel19(V, 2);                                                  \
        r4.w = sel19(V, 3);                                                  \
        *(float4 *)(out + (size_t)((d0 + (ZO)) * H + h) * W + w0) = r4;      \
    } while (0)

    // Pipeline: plane p lives in set (p & 1); slot for plane p = p % 3.
    ISSUE(0, mvA);
    ISSUE(1, mvB);
    COMMIT(mvA, 0);
    ISSUE(2, mvA);
    COMMIT(mvB, 1);
    ISSUE(3, mvB);

    // zo = 0: commit plane 2, prefetch plane 4, compute.
    COMMIT(mvA, 2);
    ISSUE(4, mvA);
    COMPUTE(0, 0, 1, 2);

    // zo = 1: commit plane 3, prefetch plane 5, compute.
    COMMIT(mvB, 0);
    ISSUE(5, mvB);
    COMPUTE(1, 1, 2, 0);

    // zo = 2: commit plane 4, compute.
    COMMIT(mvA, 1);
    COMPUTE(2, 2, 0, 1);

    // zo = 3: commit plane 5, compute.
    COMMIT(mvB, 2);
    COMPUTE(3, 0, 1, 2);

#undef ISSUE
#undef COMMIT
#undef COMPUTE
}

extern "C" void kernel_launch(void *const *d_in, const int *in_sizes, int n_in,
                              void *d_out, int out_size, void *d_ws,
                              size_t ws_size, hipStream_t stream) {
    const float *x = (const float *)d_in[0];
    float *out = (float *)d_out;
    dim3 block(64, 4, 1);
    dim3 grid(1, 256 / 4, 64 / 4);
    median3d_kernel<<<grid, block, 0, stream>>>(x, out);
}